// Round 9
// baseline (268.865 us; speedup 1.0000x reference)
//
#include <hip/hip_runtime.h>

#define V_N 4096
#define C_N 32
#define T_N 512

typedef float f32x4 __attribute__((ext_vector_type(4)));
typedef __bf16 bf16x8 __attribute__((ext_vector_type(8)));

// ---------------------------------------------------------------------------
// Pre-pass: split Ve into hi/lo bf16 packed in MFMA A-fragment order:
//   o -> tile=(t/16)*16+(k/32), lane l, elem e:
//   t = (tile>>4)*16 + (l&15),  k = (tile&15)*32 + (l>>4)*8 + e
__global__ __launch_bounds__(256) void k_pre(const float* __restrict__ Ve,
                                             __bf16* __restrict__ VeHi,
                                             __bf16* __restrict__ VeLo) {
    int o = blockIdx.x * 256 + threadIdx.x;   // 0..262143
    int e = o & 7, l = (o >> 3) & 63, tile = o >> 9;
    int kk = tile & 15, tt = tile >> 4;
    int t = tt * 16 + (l & 15);
    int k = kk * 32 + (l >> 4) * 8 + e;
    float v = Ve[(size_t)t * T_N + k];
    __bf16 h = (__bf16)v;
    VeHi[o] = h;
    VeLo[o] = (__bf16)(v - (float)h);
}

// ---------------------------------------------------------------------------
// Streaming x-pass: block = 16 contiguous v, 512 threads (thread = one t).
// vi-outer / c-inner: each block reads its 1MB x-segment as 16 sequential
// 64KB sweeps (no strided bursts). Per block:
//   partT[vc][c][t] = sum_{vi} x[v0+vi,c,t]*U1[v0+vi]   (accT[32] in regs)
//   partG[vc][c][t] = sum_{vi} rhs[vi]*U2[c,v0+vi]      (rhs[16] in regs)
//     rhs[vi] = sum_c x[v0+vi,c,t]*U3[c]
__global__ __launch_bounds__(512, 2) void k_rt(const float* __restrict__ x,
                                               const float* __restrict__ U1,
                                               const float* __restrict__ U2,
                                               const float* __restrict__ U3,
                                               float* __restrict__ partT,
                                               float* __restrict__ partG) {
    const int vc = blockIdx.x;        // 0..255, 16 v each
    const int t = threadIdx.x;        // 0..511
    const int v0 = vc * 16;
    const float* xb = x + (size_t)v0 * (C_N * T_N) + t;

    float accT[C_N];
#pragma unroll
    for (int c = 0; c < C_N; ++c) accT[c] = 0.f;
    float rhs[16];

#pragma unroll
    for (int vi = 0; vi < 16; ++vi) {
        float u1 = U1[v0 + vi];
        float racc = 0.f;
        const float* xv = xb + (size_t)vi * (C_N * T_N);
#pragma unroll
        for (int c = 0; c < C_N; ++c) {
            float xval = xv[c * T_N];
            accT[c] = fmaf(xval, u1, accT[c]);
            racc = fmaf(xval, U3[c], racc);
        }
        rhs[vi] = racc;
    }

    const size_t pbase = ((size_t)vc * C_N) * T_N + t;
#pragma unroll
    for (int c = 0; c < C_N; ++c)
        partT[pbase + (size_t)c * T_N] = accT[c];
#pragma unroll
    for (int c = 0; c < C_N; ++c) {
        float g = 0.f;
#pragma unroll
        for (int vi = 0; vi < 16; ++vi)
            g = fmaf(rhs[vi], U2[(size_t)c * V_N + v0 + vi], g);
        partG[pbase + (size_t)c * T_N] = g;
    }
}

// ---------------------------------------------------------------------------
// Fixed-order reduce of 256 chunk-partials -> tmpT[32][512], Gc[32][512].
// 8192 f32x4 outputs (T:0..4095, G:4096..8191); 8 threads per output
// (32-chunk segments each) + LDS combine. Deterministic.
__global__ __launch_bounds__(128) void k_red(const float* __restrict__ partT,
                                             const float* __restrict__ partG,
                                             float* __restrict__ tmpT,
                                             float* __restrict__ Gc) {
    __shared__ f32x4 red[16][8];
    int oid = threadIdx.x >> 3;               // 0..15
    int seg = threadIdx.x & 7;                // 0..7
    int o = blockIdx.x * 16 + oid;            // 0..8191
    int isG = o >> 12;
    int oo = o & 4095;                        // f32x4 slot in [32][128]
    int c = oo >> 7;
    int tq = oo & 127;                        // t = tq*4
    const float* src = isG ? partG : partT;
    size_t base = (size_t)c * T_N + tq * 4;
    f32x4 s = (f32x4)0.f;
#pragma unroll 4
    for (int vc = seg * 32; vc < seg * 32 + 32; ++vc)
        s += *(const f32x4*)&src[base + (size_t)vc * (C_N * T_N)];
    red[oid][seg] = s;
    __syncthreads();
    if (seg == 0) {
        f32x4 tot = red[oid][0];
#pragma unroll
        for (int k = 1; k < 8; ++k) tot += red[oid][k];
        float* dst = isG ? Gc : tmpT;
        *(f32x4*)&dst[c * T_N + tq * 4] = tot;
    }
}

// ---------------------------------------------------------------------------
// P[s][r] = sum_c Gc[c][s] * tmpT[c][r]    (K=32 tiny GEMM, fp32)
__global__ __launch_bounds__(256) void k_P2(const float* __restrict__ Gc,
                                            const float* __restrict__ tmpT,
                                            float* __restrict__ P) {
    __shared__ float Gs[32][64];
    __shared__ float Ts[32][64];
    int rbase = blockIdx.x * 64, sbase = blockIdx.y * 64;
    int tid = threadIdx.x;
    int tx = tid & 15, ty = tid >> 4;
    for (int i = tid; i < 2048; i += 256) {
        int cc = i >> 6, j = i & 63;
        Gs[cc][j] = Gc[cc * T_N + sbase + j];
        Ts[cc][j] = tmpT[cc * T_N + rbase + j];
    }
    __syncthreads();
    float acc[4][4] = {};
#pragma unroll
    for (int cc = 0; cc < 32; ++cc) {
        float a[4], b[4];
#pragma unroll
        for (int i = 0; i < 4; ++i) a[i] = Gs[cc][ty * 4 + i];
#pragma unroll
        for (int j = 0; j < 4; ++j) b[j] = Ts[cc][tx * 4 + j];
#pragma unroll
        for (int i = 0; i < 4; ++i)
#pragma unroll
            for (int j = 0; j < 4; ++j) acc[i][j] = fmaf(a[i], b[j], acc[i][j]);
    }
#pragma unroll
    for (int i = 0; i < 4; ++i) {
        f32x4 vv = {acc[i][0], acc[i][1], acc[i][2], acc[i][3]};
        *(f32x4*)&P[(size_t)(sbase + ty * 4 + i) * T_N + rbase + tx * 4] = vv;
    }
}

// ---------------------------------------------------------------------------
// Fused: per block (c, 32-wide r tile), all t (512 blocks, 2 blocks/CU):
//   S[s][r] = sigmoid(P[s][r] + be[c][s][r])   (bf16, LDS 32KB, XOR-swizzled)
//   E[t][r] = sum_s (VeHi+VeLo)[t][s] * S[s][r]  via MFMA 16x16x32 bf16
//   out[c][t][r] = softmax_t(E)
// 8 waves = 4(t) x 2(r); per wave 128t x 16r = 8x1 tiles.
__global__ __launch_bounds__(512, 4) void k_fused(const float* __restrict__ P,
                                                  const float* __restrict__ be,
                                                  const __bf16* __restrict__ VeHi,
                                                  const __bf16* __restrict__ VeLo,
                                                  float* __restrict__ out) {
    __shared__ __bf16 S[32][512];   // 32KB: S^T layout [r][s], swizzled
    const int rbase = blockIdx.x * 32;
    const int c = blockIdx.y;
    const int tid = threadIdx.x;
    const size_t cTT = (size_t)c * T_N * T_N;

    // ---- phase 1: sigmoid once per element (f32x4 loads), S^T bf16 swizzled
    {
        int r4 = (tid & 7) * 4;
        int s0 = tid >> 3;          // 0..63
        for (int i = 0; i < 8; ++i) {
            int s = i * 64 + s0;
            size_t off = (size_t)s * T_N + rbase + r4;
            f32x4 pv = *(const f32x4*)&P[off];
            f32x4 bv = *(const f32x4*)&be[cTT + off];
#pragma unroll
            for (int j = 0; j < 4; ++j) {
                float vv = pv[j] + bv[j];
                float sg = 1.0f / (1.0f + __expf(-vv));
                int rl = r4 + j;
                S[rl][s ^ ((rl & 7) << 3)] = (__bf16)sg;
            }
        }
    }
    __syncthreads();

    const int lane = tid & 63;
    const int w = tid >> 6;     // 0..7
    const int wt = w & 3;       // t-wave: 128 rows each
    const int wr = w >> 2;      // r-wave: 16 cols each
    const int lhi = lane >> 4;  // 0..3
    const int llo = lane & 15;

    const bf16x8* fragHi = (const bf16x8*)VeHi;
    const bf16x8* fragLo = (const bf16x8*)VeLo;

    f32x4 acc[8];
#pragma unroll
    for (int mi = 0; mi < 8; ++mi) acc[mi] = (f32x4)0.f;

    // ---- phase 2: K loop (s), A = packed Ve frags (L2-hot), B from LDS
    for (int k0 = 0; k0 < T_N; k0 += 32) {
        int rr = wr * 16 + llo;
        int g = (k0 >> 3) + lhi;
        bf16x8 b = *(const bf16x8*)&S[rr][(g ^ (rr & 7)) << 3];
#pragma unroll
        for (int mi = 0; mi < 8; ++mi) {
            int tile = (wt * 8 + mi) * 16 + (k0 >> 5);
            bf16x8 ah = fragHi[tile * 64 + lane];
            bf16x8 al = fragLo[tile * 64 + lane];
            acc[mi] = __builtin_amdgcn_mfma_f32_16x16x32_bf16(ah, b, acc[mi], 0, 0, 0);
            acc[mi] = __builtin_amdgcn_mfma_f32_16x16x32_bf16(al, b, acc[mi], 0, 0, 0);
        }
    }
    __syncthreads();            // done with S; reuse as reduction buffers

    float* red = (float*)&S[0][0];  // [0..127]=max, [128..255]=sum
    float gmax, gsum;

    // ---- phase 3a: column max over t
    {
        float m = -3.4e38f;
#pragma unroll
        for (int mi = 0; mi < 8; ++mi)
#pragma unroll
            for (int q = 0; q < 4; ++q) m = fmaxf(m, acc[mi][q]);
        m = fmaxf(m, __shfl_xor(m, 16));
        m = fmaxf(m, __shfl_xor(m, 32));
        if (lane < 16) red[wt * 32 + wr * 16 + llo] = m;
    }
    __syncthreads();
    {
        int col = wr * 16 + llo;
        gmax = fmaxf(fmaxf(red[col], red[32 + col]),
                     fmaxf(red[64 + col], red[96 + col]));
    }
    // ---- phase 3b: exp + column sum
    {
        float ssum = 0.f;
#pragma unroll
        for (int mi = 0; mi < 8; ++mi)
#pragma unroll
            for (int q = 0; q < 4; ++q) {
                float e = __expf(acc[mi][q] - gmax);
                acc[mi][q] = e;
                ssum += e;
            }
        ssum += __shfl_xor(ssum, 16);
        ssum += __shfl_xor(ssum, 32);
        if (lane < 16) red[128 + wt * 32 + wr * 16 + llo] = ssum;
    }
    __syncthreads();
    {
        int col = wr * 16 + llo;
        gsum = 1.0f / (red[128 + col] + red[128 + 32 + col] +
                       red[128 + 64 + col] + red[128 + 96 + col]);
    }
    // ---- phase 3c: write normalized output
    {
        int rg = rbase + wr * 16 + llo;
#pragma unroll
        for (int mi = 0; mi < 8; ++mi)
#pragma unroll
            for (int q = 0; q < 4; ++q) {
                int t = wt * 128 + mi * 16 + lhi * 4 + q;
                out[cTT + (size_t)t * T_N + rg] = acc[mi][q] * gsum;
            }
    }
}

// ---------------------------------------------------------------------------
extern "C" void kernel_launch(void* const* d_in, const int* in_sizes, int n_in,
                              void* d_out, int out_size, void* d_ws, size_t ws_size,
                              hipStream_t stream) {
    const float* x  = (const float*)d_in[0];
    const float* U1 = (const float*)d_in[1];
    const float* U2 = (const float*)d_in[2];
    const float* U3 = (const float*)d_in[3];
    const float* be = (const float*)d_in[4];
    const float* Ve = (const float*)d_in[5];
    float* out = (float*)d_out;

    float* ws    = (float*)d_ws;
    float* partT = ws;                        // 256*32*512 = 4194304 floats
    float* partG = ws + 4194304;              // 4194304
    float* P     = ws + 8388608;              // 262144
    __bf16* VeHi = (__bf16*)(ws + 8650752);   // 262144 bf16 (131072 slots)
    __bf16* VeLo = (__bf16*)(ws + 8781824);   // 262144 bf16
    float* tmpT  = ws + 8912896;              // 16384
    float* Gc    = ws + 8929280;              // 16384
    // total ~8945664 floats ~= 35.8 MB

    k_pre <<<1024, 256, 0, stream>>>(Ve, VeHi, VeLo);
    k_rt  <<<256, 512, 0, stream>>>(x, U1, U2, U3, partT, partG);
    k_red <<<512, 128, 0, stream>>>(partT, partG, tmpT, Gc);
    k_P2  <<<dim3(8, 8), 256, 0, stream>>>(Gc, tmpT, P);
    k_fused<<<dim3(16, C_N), 512, 0, stream>>>(P, be, VeHi, VeLo, out);
}

// Round 11
// 123.560 us; speedup vs baseline: 2.1760x; 2.1760x over previous
//
#include <hip/hip_runtime.h>

#define V_N 4096
#define C_N 32
#define T_N 512

typedef float f32x4 __attribute__((ext_vector_type(4)));
typedef __bf16 bf16x8 __attribute__((ext_vector_type(8)));

__device__ inline f32x4 fma4(f32x4 a, float b, f32x4 c) {
    f32x4 r;
    r.x = fmaf(a.x, b, c.x); r.y = fmaf(a.y, b, c.y);
    r.z = fmaf(a.z, b, c.z); r.w = fmaf(a.w, b, c.w);
    return r;
}

// ---------------------------------------------------------------------------
// Pre-pass: split Ve into hi/lo bf16 packed in MFMA A-fragment order:
//   o -> tile=(t/16)*16+(k/32), lane l, elem e:
//   t = (tile>>4)*16 + (l&15),  k = (tile&15)*32 + (l>>4)*8 + e
__global__ __launch_bounds__(256) void k_pre(const float* __restrict__ Ve,
                                             __bf16* __restrict__ VeHi,
                                             __bf16* __restrict__ VeLo) {
    int o = blockIdx.x * 256 + threadIdx.x;   // 0..262143
    int e = o & 7, l = (o >> 3) & 63, tile = o >> 9;
    int kk = tile & 15, tt = tile >> 4;
    int t = tt * 16 + (l & 15);
    int k = kk * 32 + (l >> 4) * 8 + e;
    float v = Ve[(size_t)t * T_N + k];
    __bf16 h = (__bf16)v;
    VeHi[o] = h;
    VeLo[o] = (__bf16)(v - (float)h);
}

// ---------------------------------------------------------------------------
// Streaming x-pass with CONTIGUOUS wave sweeps.
// Block = 16 v-planes (64KB each); wave w reads rows (w*16+j)*1KB, j=0..15 —
// 16KB contiguous per wave per plane, block covers the whole plane densely.
// Element map: c = w*8 + (j>>1), t = (j&1)*256 + l*4.
//   accT[i][s]: partial sum_{vi} x*U1 for this thread's (c,t) slots
//   racc: partial rhs over this wave's 8 c; combined across 4 waves via LDS
//   gacc[i][s]: partial G = sum_{vi} rhs*U2[c,v]
__global__ __launch_bounds__(256, 1) void k_rt(const float* __restrict__ x,
                                               const float* __restrict__ U1,
                                               const float* __restrict__ U2,
                                               const float* __restrict__ U3,
                                               float* __restrict__ partT,
                                               float* __restrict__ partG) {
    const int vc = blockIdx.x;            // 0..255, 16 v each
    const int tid = threadIdx.x;
    const int w = tid >> 6;               // wave 0..3
    const int l = tid & 63;               // lane
    const int v0 = vc * 16;

    __shared__ f32x4 lsum[2][4][2][64];   // [buf][wave][t-half][lane] = 16KB

    float u3loc[8];
#pragma unroll
    for (int i = 0; i < 8; ++i) u3loc[i] = U3[w * 8 + i];

    f32x4 accT[8][2];
    f32x4 gacc[8][2];
#pragma unroll
    for (int i = 0; i < 8; ++i)
#pragma unroll
        for (int s = 0; s < 2; ++s) {
            accT[i][s] = (f32x4)0.f;
            gacc[i][s] = (f32x4)0.f;
        }

    const float* xplane0 = x + (size_t)v0 * (C_N * T_N);
#pragma unroll 1
    for (int vi = 0; vi < 16; ++vi) {
        const float* xp = xplane0 + (size_t)vi * (C_N * T_N);
        float u1 = U1[v0 + vi];
        int buf = vi & 1;
        f32x4 racc0 = (f32x4)0.f, racc1 = (f32x4)0.f;
#pragma unroll
        for (int j = 0; j < 16; ++j) {
            f32x4 xv = *(const f32x4*)(xp + (size_t)(w * 16 + j) * 256 + l * 4);
            int i = j >> 1;
            if ((j & 1) == 0) {
                accT[i][0] = fma4(xv, u1, accT[i][0]);
                racc0 = fma4(xv, u3loc[i], racc0);
            } else {
                accT[i][1] = fma4(xv, u1, accT[i][1]);
                racc1 = fma4(xv, u3loc[i], racc1);
            }
        }
        lsum[buf][w][0][l] = racc0;
        lsum[buf][w][1][l] = racc1;
        __syncthreads();
        f32x4 rhs0 = (lsum[buf][0][0][l] + lsum[buf][1][0][l]) +
                     (lsum[buf][2][0][l] + lsum[buf][3][0][l]);
        f32x4 rhs1 = (lsum[buf][0][1][l] + lsum[buf][1][1][l]) +
                     (lsum[buf][2][1][l] + lsum[buf][3][1][l]);
        float u2loc[8];
#pragma unroll
        for (int i = 0; i < 8; ++i)
            u2loc[i] = U2[(size_t)(w * 8 + i) * V_N + v0 + vi];
#pragma unroll
        for (int i = 0; i < 8; ++i) {
            gacc[i][0] = fma4(rhs0, u2loc[i], gacc[i][0]);
            gacc[i][1] = fma4(rhs1, u2loc[i], gacc[i][1]);
        }
    }

    const size_t pbase = (size_t)vc * (C_N * T_N);
#pragma unroll
    for (int i = 0; i < 8; ++i)
#pragma unroll
        for (int s = 0; s < 2; ++s) {
            size_t off = pbase + (size_t)(w * 8 + i) * T_N + s * 256 + l * 4;
            *(f32x4*)&partT[off] = accT[i][s];
            *(f32x4*)&partG[off] = gacc[i][s];
        }
}

// ---------------------------------------------------------------------------
// Fixed-order reduce of 256 chunk-partials -> tmpT[32][512], Gc[32][512].
// 8192 f32x4 outputs (T:0..4095, G:4096..8191); 8 threads per output
// (32-chunk segments each) + LDS combine. Deterministic.
__global__ __launch_bounds__(128) void k_red(const float* __restrict__ partT,
                                             const float* __restrict__ partG,
                                             float* __restrict__ tmpT,
                                             float* __restrict__ Gc) {
    __shared__ f32x4 red[16][8];
    int oid = threadIdx.x >> 3;               // 0..15
    int seg = threadIdx.x & 7;                // 0..7
    int o = blockIdx.x * 16 + oid;            // 0..8191
    int isG = o >> 12;
    int oo = o & 4095;                        // f32x4 slot in [32][128]
    int c = oo >> 7;
    int tq = oo & 127;                        // t = tq*4
    const float* src = isG ? partG : partT;
    size_t base = (size_t)c * T_N + tq * 4;
    f32x4 s = (f32x4)0.f;
#pragma unroll 4
    for (int vc = seg * 32; vc < seg * 32 + 32; ++vc)
        s += *(const f32x4*)&src[base + (size_t)vc * (C_N * T_N)];
    red[oid][seg] = s;
    __syncthreads();
    if (seg == 0) {
        f32x4 tot = red[oid][0];
#pragma unroll
        for (int k = 1; k < 8; ++k) tot += red[oid][k];
        float* dst = isG ? Gc : tmpT;
        *(f32x4*)&dst[c * T_N + tq * 4] = tot;
    }
}

// ---------------------------------------------------------------------------
// P[s][r] = sum_c Gc[c][s] * tmpT[c][r]    (K=32 tiny GEMM, fp32)
__global__ __launch_bounds__(256) void k_P2(const float* __restrict__ Gc,
                                            const float* __restrict__ tmpT,
                                            float* __restrict__ P) {
    __shared__ float Gs[32][64];
    __shared__ float Ts[32][64];
    int rbase = blockIdx.x * 64, sbase = blockIdx.y * 64;
    int tid = threadIdx.x;
    int tx = tid & 15, ty = tid >> 4;
    for (int i = tid; i < 2048; i += 256) {
        int cc = i >> 6, j = i & 63;
        Gs[cc][j] = Gc[cc * T_N + sbase + j];
        Ts[cc][j] = tmpT[cc * T_N + rbase + j];
    }
    __syncthreads();
    float acc[4][4] = {};
#pragma unroll
    for (int cc = 0; cc < 32; ++cc) {
        float a[4], b[4];
#pragma unroll
        for (int i = 0; i < 4; ++i) a[i] = Gs[cc][ty * 4 + i];
#pragma unroll
        for (int j = 0; j < 4; ++j) b[j] = Ts[cc][tx * 4 + j];
#pragma unroll
        for (int i = 0; i < 4; ++i)
#pragma unroll
            for (int j = 0; j < 4; ++j) acc[i][j] = fmaf(a[i], b[j], acc[i][j]);
    }
#pragma unroll
    for (int i = 0; i < 4; ++i) {
        f32x4 vv = {acc[i][0], acc[i][1], acc[i][2], acc[i][3]};
        *(f32x4*)&P[(size_t)(sbase + ty * 4 + i) * T_N + rbase + tx * 4] = vv;
    }
}

// ---------------------------------------------------------------------------
// Fused: per block (c, 32-wide r tile), all t (512 blocks, 2 blocks/CU):
//   S[s][r] = sigmoid(P[s][r] + be[c][s][r])   (bf16, LDS 32KB, XOR-swizzled)
//   E[t][r] = sum_s (VeHi+VeLo)[t][s] * S[s][r]  via MFMA 16x16x32 bf16
//   out[c][t][r] = softmax_t(E)
// 8 waves = 4(t) x 2(r); per wave 128t x 16r = 8x1 tiles.
__global__ __launch_bounds__(512, 4) void k_fused(const float* __restrict__ P,
                                                  const float* __restrict__ be,
                                                  const __bf16* __restrict__ VeHi,
                                                  const __bf16* __restrict__ VeLo,
                                                  float* __restrict__ out) {
    __shared__ __bf16 S[32][512];   // 32KB: S^T layout [r][s], swizzled
    const int rbase = blockIdx.x * 32;
    const int c = blockIdx.y;
    const int tid = threadIdx.x;
    const size_t cTT = (size_t)c * T_N * T_N;

    // ---- phase 1: sigmoid once per element (f32x4 loads), S^T bf16 swizzled
    {
        int r4 = (tid & 7) * 4;
        int s0 = tid >> 3;          // 0..63
        for (int i = 0; i < 8; ++i) {
            int s = i * 64 + s0;
            size_t off = (size_t)s * T_N + rbase + r4;
            f32x4 pv = *(const f32x4*)&P[off];
            f32x4 bv = *(const f32x4*)&be[cTT + off];
#pragma unroll
            for (int j = 0; j < 4; ++j) {
                float vv = pv[j] + bv[j];
                float sg = 1.0f / (1.0f + __expf(-vv));
                int rl = r4 + j;
                S[rl][s ^ ((rl & 7) << 3)] = (__bf16)sg;
            }
        }
    }
    __syncthreads();

    const int lane = tid & 63;
    const int w = tid >> 6;     // 0..7
    const int wt = w & 3;       // t-wave: 128 rows each
    const int wr = w >> 2;      // r-wave: 16 cols each
    const int lhi = lane >> 4;  // 0..3
    const int llo = lane & 15;

    const bf16x8* fragHi = (const bf16x8*)VeHi;
    const bf16x8* fragLo = (const bf16x8*)VeLo;

    f32x4 acc[8];
#pragma unroll
    for (int mi = 0; mi < 8; ++mi) acc[mi] = (f32x4)0.f;

    // ---- phase 2: K loop (s), A = packed Ve frags (L2-hot), B from LDS
    for (int k0 = 0; k0 < T_N; k0 += 32) {
        int rr = wr * 16 + llo;
        int g = (k0 >> 3) + lhi;
        bf16x8 b = *(const bf16x8*)&S[rr][(g ^ (rr & 7)) << 3];
#pragma unroll
        for (int mi = 0; mi < 8; ++mi) {
            int tile = (wt * 8 + mi) * 16 + (k0 >> 5);
            bf16x8 ah = fragHi[tile * 64 + lane];
            bf16x8 al = fragLo[tile * 64 + lane];
            acc[mi] = __builtin_amdgcn_mfma_f32_16x16x32_bf16(ah, b, acc[mi], 0, 0, 0);
            acc[mi] = __builtin_amdgcn_mfma_f32_16x16x32_bf16(al, b, acc[mi], 0, 0, 0);
        }
    }
    __syncthreads();            // done with S; reuse as reduction buffers

    float* red = (float*)&S[0][0];  // [0..127]=max, [128..255]=sum
    float gmax, gsum;

    // ---- phase 3a: column max over t
    {
        float m = -3.4e38f;
#pragma unroll
        for (int mi = 0; mi < 8; ++mi)
#pragma unroll
            for (int q = 0; q < 4; ++q) m = fmaxf(m, acc[mi][q]);
        m = fmaxf(m, __shfl_xor(m, 16));
        m = fmaxf(m, __shfl_xor(m, 32));
        if (lane < 16) red[wt * 32 + wr * 16 + llo] = m;
    }
    __syncthreads();
    {
        int col = wr * 16 + llo;
        gmax = fmaxf(fmaxf(red[col], red[32 + col]),
                     fmaxf(red[64 + col], red[96 + col]));
    }
    // ---- phase 3b: exp + column sum
    {
        float ssum = 0.f;
#pragma unroll
        for (int mi = 0; mi < 8; ++mi)
#pragma unroll
            for (int q = 0; q < 4; ++q) {
                float e = __expf(acc[mi][q] - gmax);
                acc[mi][q] = e;
                ssum += e;
            }
        ssum += __shfl_xor(ssum, 16);
        ssum += __shfl_xor(ssum, 32);
        if (lane < 16) red[128 + wt * 32 + wr * 16 + llo] = ssum;
    }
    __syncthreads();
    {
        int col = wr * 16 + llo;
        gsum = 1.0f / (red[128 + col] + red[128 + 32 + col] +
                       red[128 + 64 + col] + red[128 + 96 + col]);
    }
    // ---- phase 3c: write normalized output
    {
        int rg = rbase + wr * 16 + llo;
#pragma unroll
        for (int mi = 0; mi < 8; ++mi)
#pragma unroll
            for (int q = 0; q < 4; ++q) {
                int t = wt * 128 + mi * 16 + lhi * 4 + q;
                out[cTT + (size_t)t * T_N + rg] = acc[mi][q] * gsum;
            }
    }
}

// ---------------------------------------------------------------------------
extern "C" void kernel_launch(void* const* d_in, const int* in_sizes, int n_in,
                              void* d_out, int out_size, void* d_ws, size_t ws_size,
                              hipStream_t stream) {
    const float* x  = (const float*)d_in[0];
    const float* U1 = (const float*)d_in[1];
    const float* U2 = (const float*)d_in[2];
    const float* U3 = (const float*)d_in[3];
    const float* be = (const float*)d_in[4];
    const float* Ve = (const float*)d_in[5];
    float* out = (float*)d_out;

    float* ws    = (float*)d_ws;
    float* partT = ws;                        // 256*32*512 = 4194304 floats
    float* partG = ws + 4194304;              // 4194304
    float* P     = ws + 8388608;              // 262144
    __bf16* VeHi = (__bf16*)(ws + 8650752);   // 262144 bf16 (131072 slots)
    __bf16* VeLo = (__bf16*)(ws + 8781824);   // 262144 bf16
    float* tmpT  = ws + 8912896;              // 16384
    float* Gc    = ws + 8929280;              // 16384
    // total ~8945664 floats ~= 35.8 MB

    k_pre <<<1024, 256, 0, stream>>>(Ve, VeHi, VeLo);
    k_rt  <<<256, 256, 0, stream>>>(x, U1, U2, U3, partT, partG);
    k_red <<<512, 128, 0, stream>>>(partT, partG, tmpT, Gc);
    k_P2  <<<dim3(8, 8), 256, 0, stream>>>(Gc, tmpT, P);
    k_fused<<<dim3(16, C_N), 512, 0, stream>>>(P, be, VeHi, VeLo, out);
}